// Round 9
// baseline (613.279 us; speedup 1.0000x reference)
//
#include <hip/hip_runtime.h>
#include <hip/hip_fp16.h>
#include <math.h>

#define NN      100000
#define EE      1600000
#define DIN     128
#define CC      16
#define NITERS  5
#define NBLKS   100000               // 16-edge mfma blocks
#define UU      5                    // mfma blocks (chains) per wave
#define GRID_E  (NBLKS / (UU * 4))   // 5000 blocks of 256 (4 waves)
#define NEGLOGC (-2.772588722239781f)
#define QS      128.0f               // 2^7 u16 fixed-point scale (agg)
#define QINV    (1.0f / 128.0f)
#define QCLAMP  8.0f                 // > math bound 7.3 on -n: NaN guard only
#define GRID_U  782                  // ceil(2*NN / 256) update blocks

// padded node-state row: 128B = [belief f32 x16 (64B) | agg u16 x16 (32B) | pad]
#define ROWF    32                   // floats per row
#define ROWH    64                   // u16 per row
#define AGGH    32                   // u16 offset of agg within row
#define ROWU    16                   // u64 per row
#define AGGU    8                    // u64 offset of agg within row

#if __has_builtin(__builtin_amdgcn_mfma_f32_16x16x16bf16_1k)
#define USE_1K 1
#else
#define USE_1K 0
#endif

typedef float f4  __attribute__((ext_vector_type(4)));
typedef float v4f __attribute__((ext_vector_type(4)));
typedef short v4s __attribute__((ext_vector_type(4)));
typedef unsigned short u8h __attribute__((ext_vector_type(8)));
typedef unsigned long long ull;

// ---------------------------------------------------------------------------
// helpers: fp16 / bf16 <-> f32
// ---------------------------------------------------------------------------
__device__ __forceinline__ unsigned short f2h(float f) {
    return __half_as_ushort(__float2half(f));
}
__device__ __forceinline__ float h2f(unsigned short u) {
    return __half2float(__ushort_as_half(u));
}
__device__ __forceinline__ unsigned int pack_h(float lo, float hi) {
    return (unsigned int)f2h(lo) | ((unsigned int)f2h(hi) << 16);
}
__device__ __forceinline__ unsigned short f2bf(float f) {
    unsigned int u = __float_as_uint(f);
    unsigned int r = u + 0x7fffu + ((u >> 16) & 1u);   // round-nearest-even
    return (unsigned short)(r >> 16);
}

// ---------------------------------------------------------------------------
// fused setup: M = sigmoid(10*param) (+ row sums at M[256..271]);
// logb0 = log_softmax(x@W+b) -> dense logb0 AND padded belief row; agg = 0.
// W staged TRANSPOSED in LDS (round-6 win).  grid = 6250 x 256.
// ---------------------------------------------------------------------------
__global__ __launch_bounds__(256) void k_setup(
    const float* __restrict__ x, const float* __restrict__ W,
    const float* __restrict__ b, const float* __restrict__ param,
    float* __restrict__ M, float* __restrict__ logb0,
    float* __restrict__ st)
{
    __shared__ float WT[CC][132];              // W^T, padded (528B row stride)

    // cooperative W load+transpose: 2048 f32, 8 per thread (two f4 loads)
    {
        f4 w0 = *(const f4*)(W + threadIdx.x * 8);
        f4 w1 = *(const f4*)(W + threadIdx.x * 8 + 4);
#pragma unroll
        for (int i = 0; i < 4; ++i) {
            int idx = threadIdx.x * 8 + i;
            WT[idx & 15][idx >> 4] = w0[i];
        }
#pragma unroll
        for (int i = 0; i < 4; ++i) {
            int idx = threadIdx.x * 8 + 4 + i;
            WT[idx & 15][idx >> 4] = w1[i];
        }
    }

    if (blockIdx.x == 0 && threadIdx.x < CC * (CC + 1) / 2) {
        int i = threadIdx.x;
        int r = 0;
        while ((r + 1) * (r + 2) / 2 <= i) ++r;
        int c = i - r * (r + 1) / 2;
        float z = param[i] * 10.0f;
        float s = 1.0f / (1.0f + __expf(-z));
        M[r * CC + c] = s;
        if (r != c) M[c * CC + r] = s;
    }

    __syncthreads();   // WT ready (all blocks); M part-1 visible (block 0)

    if (blockIdx.x == 0 && threadIdx.x < CC) {  // row sums for the T shortcut
        float s = 0.f;
        for (int c = 0; c < CC; ++c) s += M[threadIdx.x * CC + c];
        M[256 + threadIdx.x] = s;
    }

    int idx = blockIdx.x * 256 + threadIdx.x;
    int node = idx >> 4;
    int cls  = idx & 15;

    ((unsigned short*)st)[(long)node * ROWH + AGGH + cls] = 0;   // agg = 0

    const f4* xr4 = (const f4*)(x + (long)node * DIN);
    const f4* wr4 = (const f4*)(&WT[cls][0]);   // 16B-aligned (528B stride)
    float acc = b[cls];
#pragma unroll 8
    for (int k4 = 0; k4 < DIN / 4; ++k4) {
        f4 xv = __builtin_nontemporal_load(xr4 + k4);   // x streamed once
        f4 wv = wr4[k4];
        acc = fmaf(xv.x, wv.x, acc);
        acc = fmaf(xv.y, wv.y, acc);
        acc = fmaf(xv.z, wv.z, acc);
        acc = fmaf(xv.w, wv.w, acc);
    }
    float m = acc;
    for (int off = 8; off; off >>= 1) m = fmaxf(m, __shfl_xor(m, off, 16));
    float s = __expf(acc - m);
    for (int off = 8; off; off >>= 1) s += __shfl_xor(s, off, 16);
    float lb = acc - m - __logf(s);
    logb0[idx] = lb;                            // dense (streamed by k_update)
    st[(long)node * ROWF + cls] = lb;           // padded belief (iter-0 input)
}

// ---------------------------------------------------------------------------
// Edge kernel, swapped-operand MFMA layout (HW-verified rounds 2-8).
//
// ROUND-9 CHANGE: node-state CO-LOCATION.  belief (64B f32x16) and agg
// (32B u16x16) now live in ONE padded 128B row.  A 16-edge block's gather
// set and scatter set are the SAME 16 nodes (dst[m] = src[m^1]), so the
// block now touches 16 distinct HBM lines instead of 32 — the belief line
// fetch and the pair-edge's agg RMW share the line / DRAM row.  Tests the
// "random HBM line traffic" wall (FETCH+WRITE = 2.31 TB/s at r8).
// ---------------------------------------------------------------------------
template <bool RD_MSG, bool WR_MSG>
__global__ __launch_bounds__(256) void k_edges_s(
    const int* __restrict__ esrc, const float* __restrict__ st,
    const float* __restrict__ Mg, ull* __restrict__ msg8)
{
    const int lane = threadIdx.x & 63;
    const int wid  = blockIdx.x * 4 + (threadIdx.x >> 6);
    const int m    = lane & 15;
    const int q    = lane >> 4;

    ull* stw = (ull*)st;                       // for atomics into agg region

    // atomic permutation constants (lane-invariant)
    const int ed = lane >> 2;                  // edge this lane covers
    const int j4 = lane & 3;                   // u64 index within agg sub-row
    const int sl = (j4 << 4) | ed;             // source lane for (ed, j4)

#if USE_1K
    // A-operand fragment: A[row=m][k=4q+j] = M[m][4q+j] (M symmetric)
    v4s mfrag;
#pragma unroll
    for (int jj = 0; jj < 4; ++jj)
        mfrag[jj] = (short)f2bf(Mg[m * CC + 4 * q + jj]);
#endif
    f4 rs = *(const f4*)(Mg + 256 + 4 * q);    // rowsums for k = 4q..4q+3

    // ---- phase 1: independent chain heads (UU chains) ----
    int srcv[UU];
    ull mw[UU];
#pragma unroll
    for (int u = 0; u < UU; ++u) {
        const long blk = (long)wid * UU + u;
        srcv[u] = __builtin_nontemporal_load(esrc + blk * 16 + m);
        if (RD_MSG)
            mw[u] = __builtin_nontemporal_load(msg8 + blk * 64 + q * 16 + (m ^ 1));
    }
    // ---- phase 2: dependent gathers, still before any compute ----
    f4 lb[UU];
#pragma unroll
    for (int u = 0; u < UU; ++u)
        lb[u] = *(const f4*)(st + (long)srcv[u] * ROWF + 4 * q);

    // ---- phase 3: compute (UU independent chains in flight) ----
#pragma unroll
    for (int u = 0; u < UU; ++u) {
        const long blk = (long)wid * UU + u;

        float mv0 = 0.f, mv1 = 0.f, mv2 = 0.f, mv3 = 0.f;
        if (RD_MSG) {
            mv0 = h2f((unsigned short)(mw[u] & 0xffffu));
            mv1 = h2f((unsigned short)((mw[u] >> 16) & 0xffffu));
            mv2 = h2f((unsigned short)((mw[u] >> 32) & 0xffffu));
            mv3 = h2f((unsigned short)(mw[u] >> 48));
        }

        float e0 = __expf(lb[u].x - mv0);   // t = belief[src] - msg[reverse]
        float e1f = __expf(lb[u].y - mv1);
        float e2 = __expf(lb[u].z - mv2);
        float e3 = __expf(lb[u].w - mv3);

        float Tm = e0 * rs.x;
        Tm = fmaf(e1f, rs.y, Tm);
        Tm = fmaf(e2, rs.z, Tm);
        Tm = fmaf(e3, rs.w, Tm);
        Tm += __shfl_xor(Tm, 16, 64);
        Tm += __shfl_xor(Tm, 32, 64);
        float lT = __logf(Tm);             // log T[edge m], lane-local

        float D0, D1, D2, D3;
#if USE_1K
        v4s a;
        a[0] = (short)f2bf(e0); a[1] = (short)f2bf(e1f);
        a[2] = (short)f2bf(e2); a[3] = (short)f2bf(e3);
        v4f acc = {0.f, 0.f, 0.f, 0.f};
        // swapped operands: D[row=class 4q+i][col=edge m]
        v4f D = __builtin_amdgcn_mfma_f32_16x16x16bf16_1k(mfrag, a, acc, 0, 0, 0);
        D0 = D[0]; D1 = D[1]; D2 = D[2]; D3 = D[3];
#else
        // fallback: cross-quad broadcast + scalar dot (same lane layout)
        float ee[4] = {e0, e1f, e2, e3};
        float g1[4], g2[4], g3[4];
#pragma unroll
        for (int jj = 0; jj < 4; ++jj) {
            g1[jj] = __shfl_xor(ee[jj], 16, 64);
            g2[jj] = __shfl_xor(ee[jj], 32, 64);
            g3[jj] = __shfl_xor(ee[jj], 48, 64);
        }
        float Dv[4];
#pragma unroll
        for (int i = 0; i < 4; ++i) {
            const float* Mr = Mg + (4 * q + i) * CC;
            float d = 0.f;
#pragma unroll
            for (int jj = 0; jj < 4; ++jj) {
                d = fmaf(Mr[4 * q + jj],       ee[jj], d);
                d = fmaf(Mr[4 * (q ^ 1) + jj], g1[jj], d);
                d = fmaf(Mr[4 * (q ^ 2) + jj], g2[jj], d);
                d = fmaf(Mr[4 * (q ^ 3) + jj], g3[jj], d);
            }
            Dv[i] = d;
        }
        D0 = Dv[0]; D1 = Dv[1]; D2 = Dv[2]; D3 = Dv[3];
#endif
        // normalized log-message for edge m, classes 4q..4q+3
        float n0 = __logf(D0) - lT;
        float n1 = __logf(D1) - lT;
        float n2 = __logf(D2) - lT;
        float n3 = __logf(D3) - lT;

        if (WR_MSG) {
            ull w = (ull)pack_h(n0, n1) | ((ull)pack_h(n2, n3) << 32);
            __builtin_nontemporal_store(w, msg8 + blk * 64 + q * 16 + m);
        }

        // dst(edge m) = src(edge m^1): pairs are reciprocal and adjacent
        int dstv = __shfl_xor(srcv[u], 1, 16);

        // u16 fixed-point pack: this lane holds u64 #q of edge m directly
        unsigned int q0 = (unsigned int)(fminf(fmaxf(-n0, 0.f), QCLAMP) * QS + 0.5f);
        unsigned int q1 = (unsigned int)(fminf(fmaxf(-n1, 0.f), QCLAMP) * QS + 0.5f);
        unsigned int q2 = (unsigned int)(fminf(fmaxf(-n2, 0.f), QCLAMP) * QS + 0.5f);
        unsigned int q3 = (unsigned int)(fminf(fmaxf(-n3, 0.f), QCLAMP) * QS + 0.5f);
        ull p = (ull)q0 | ((ull)q1 << 16) | ((ull)q2 << 32) | ((ull)q3 << 48);

        // permute so ONE atomic instruction covers 16 edges x 32B agg spans
        ull v = __shfl(p, sl, 64);
        int d = __shfl(dstv, ed, 16);        // dst of edge ed (q-invariant)
        atomicAdd(&stw[(long)d * ROWU + AGGU + j4], v);
    }
}

// ---------------------------------------------------------------------------
// belief = log_normalize(logb0 - QINV*agg), written back into the padded row
// (or dense out on the final iteration); resets agg.  Vectorized x8: thread t
// owns half a node row (node t>>1, half t&1); row pair exchange = shfl_xor(1).
// ---------------------------------------------------------------------------
template <bool FINAL>
__global__ __launch_bounds__(256) void k_update(
    const float* __restrict__ logb0, float* __restrict__ st,
    float* __restrict__ out)
{
    const int t = blockIdx.x * 256 + threadIdx.x;
    if (t >= 2 * NN) return;
    const int node = t >> 1;
    const int h    = t & 1;

    unsigned short* agg16 = (unsigned short*)st;
    const long ab = (long)node * ROWH + AGGH + h * 8;
    u8h av = *(const u8h*)(agg16 + ab);        // 16B aligned
    *(u8h*)(agg16 + ab) = (u8h){0,0,0,0,0,0,0,0};

    const long db = (long)node * CC + h * 8;   // dense logb0 index
    f4 l0 = *(const f4*)(logb0 + db);
    f4 l1 = *(const f4*)(logb0 + db + 4);

    float v[8];
#pragma unroll
    for (int i = 0; i < 4; ++i) {
        v[i]     = fmaf(-(float)av[i],     QINV, l0[i]);
        v[4 + i] = fmaf(-(float)av[4 + i], QINV, l1[i]);
    }
    float mx = v[0];
#pragma unroll
    for (int i = 1; i < 8; ++i) mx = fmaxf(mx, v[i]);
    mx = fmaxf(mx, __shfl_xor(mx, 1, 64));     // other half of the node row

    float s = 0.f;
#pragma unroll
    for (int i = 0; i < 8; ++i) s += __expf(v[i] - mx);
    s += __shfl_xor(s, 1, 64);
    float lz = mx + __logf(s);

    f4 o0, o1;
#pragma unroll
    for (int i = 0; i < 4; ++i) { o0[i] = v[i] - lz; o1[i] = v[4 + i] - lz; }
    if (FINAL) {
        *(f4*)(out + db)     = o0;
        *(f4*)(out + db + 4) = o1;
    } else {
        float* bp = st + (long)node * ROWF + h * 8;
        *(f4*)(bp)     = o0;
        *(f4*)(bp + 4) = o1;
    }
}

// ---------------------------------------------------------------------------
extern "C" void kernel_launch(void* const* d_in, const int* in_sizes, int n_in,
                              void* d_out, int out_size, void* d_ws, size_t ws_size,
                              hipStream_t stream)
{
    const float* x     = (const float*)d_in[0];
    const float* W     = (const float*)d_in[1];
    const float* b     = (const float*)d_in[2];
    const float* param = (const float*)d_in[3];
    const int*   eidx  = (const int*)d_in[4];
    const int*   esrc  = eidx;                 // edst derived via pair shuffle

    // byte-offset layout (node-state rows 128B-aligned)
    char* ws = (char*)d_ws;
    float* M     = (float*)ws;                            // [0, 1152)
    float* st    = (float*)(ws + 4096);                   // NN x 128B padded rows
    float* logb0 = (float*)(ws + 4096 + 12800000);        // N*C f32 dense
    ull*   msg8  = (ull*)(ws + 4096 + 12800000 + 6400000);// NBLKS*64 u64
    float* outp  = (float*)d_out;

    k_setup<<<NN * CC / 256, 256, 0, stream>>>(x, W, b, param, M, logb0, st);

    for (int it = 0; it < NITERS; ++it) {
        if (it == 0)
            k_edges_s<false, true><<<GRID_E, 256, 0, stream>>>(
                esrc, st, M, msg8);
        else if (it == NITERS - 1)
            k_edges_s<true, false><<<GRID_E, 256, 0, stream>>>(
                esrc, st, M, msg8);
        else
            k_edges_s<true, true><<<GRID_E, 256, 0, stream>>>(
                esrc, st, M, msg8);
        if (it == NITERS - 1)
            k_update<true><<<GRID_U, 256, 0, stream>>>(logb0, st, outp);
        else
            k_update<false><<<GRID_U, 256, 0, stream>>>(logb0, st, outp);
    }
}

// Round 10
// 521.779 us; speedup vs baseline: 1.1754x; 1.1754x over previous
//
#include <hip/hip_runtime.h>
#include <hip/hip_fp16.h>
#include <math.h>

#define NN      100000
#define EE      1600000
#define DIN     128
#define CC      16
#define NITERS  5
#define NBLKS   100000               // 16-edge mfma blocks
#define UU      5                    // mfma blocks (chains) per wave
#define GRID_E  (NBLKS / (UU * 4))   // 5000 blocks of 256 (4 waves)
#define NEGLOGC (-2.772588722239781f)
#define QS      128.0f               // 2^7 u16 fixed-point scale (agg)
#define QINV    (1.0f / 128.0f)
#define QCLAMP  8.0f                 // > math bound 7.3 on -n: NaN guard only
#define GRID_U  782                  // ceil(2*NN / 256) final-update blocks

#if __has_builtin(__builtin_amdgcn_mfma_f32_16x16x16bf16_1k)
#define USE_1K 1
#else
#define USE_1K 0
#endif

typedef float f4  __attribute__((ext_vector_type(4)));
typedef float v4f __attribute__((ext_vector_type(4)));
typedef short v4s __attribute__((ext_vector_type(4)));
typedef unsigned long long ull;

// ---------------------------------------------------------------------------
// helpers: fp16 / bf16 <-> f32
// ---------------------------------------------------------------------------
__device__ __forceinline__ unsigned short f2h(float f) {
    return __half_as_ushort(__float2half(f));
}
__device__ __forceinline__ float h2f(unsigned short u) {
    return __half2float(__ushort_as_half(u));
}
__device__ __forceinline__ unsigned int pack_h(float lo, float hi) {
    return (unsigned int)f2h(lo) | ((unsigned int)f2h(hi) << 16);
}
__device__ __forceinline__ unsigned short f2bf(float f) {
    unsigned int u = __float_as_uint(f);
    unsigned int r = u + 0x7fffu + ((u >> 16) & 1u);   // round-nearest-even
    return (unsigned short)(r >> 16);
}

// ---------------------------------------------------------------------------
// fused setup: M = sigmoid(10*param) (+ row sums at M[256..271]);
// logb0 = log_softmax(x@W+b)  -> f32 dense (final pass)
//                             -> u16 seed = round(-logb0*QS) in seedq, bufA, bufB
// W staged TRANSPOSED in LDS (round-6 win).  grid = 6250 x 256.
//
// AGG-SEEDING (round-10): buffers hold A = seed + sum(quantized -msg), so the
// un-normalized belief is  v = -A*QINV  (uniform shift cancels in message
// normalization; r3-HW-verified with the mx guard).  This removes the 4
// intermediate k_update dispatches entirely.
// ---------------------------------------------------------------------------
__global__ __launch_bounds__(256) void k_setup(
    const float* __restrict__ x, const float* __restrict__ W,
    const float* __restrict__ b, const float* __restrict__ param,
    float* __restrict__ M, float* __restrict__ logb0,
    unsigned short* __restrict__ seedq,
    unsigned short* __restrict__ bufA, unsigned short* __restrict__ bufB)
{
    __shared__ float WT[CC][132];              // W^T, padded (528B row stride)

    // cooperative W load+transpose: 2048 f32, 8 per thread (two f4 loads)
    {
        f4 w0 = *(const f4*)(W + threadIdx.x * 8);
        f4 w1 = *(const f4*)(W + threadIdx.x * 8 + 4);
#pragma unroll
        for (int i = 0; i < 4; ++i) {
            int idx = threadIdx.x * 8 + i;
            WT[idx & 15][idx >> 4] = w0[i];
        }
#pragma unroll
        for (int i = 0; i < 4; ++i) {
            int idx = threadIdx.x * 8 + 4 + i;
            WT[idx & 15][idx >> 4] = w1[i];
        }
    }

    if (blockIdx.x == 0 && threadIdx.x < CC * (CC + 1) / 2) {
        int i = threadIdx.x;
        int r = 0;
        while ((r + 1) * (r + 2) / 2 <= i) ++r;
        int c = i - r * (r + 1) / 2;
        float z = param[i] * 10.0f;
        float s = 1.0f / (1.0f + __expf(-z));
        M[r * CC + c] = s;
        if (r != c) M[c * CC + r] = s;
    }

    __syncthreads();   // WT ready (all blocks); M part-1 visible (block 0)

    if (blockIdx.x == 0 && threadIdx.x < CC) {  // row sums for the T shortcut
        float s = 0.f;
        for (int c = 0; c < CC; ++c) s += M[threadIdx.x * CC + c];
        M[256 + threadIdx.x] = s;
    }

    int idx = blockIdx.x * 256 + threadIdx.x;
    int node = idx >> 4;
    int cls  = idx & 15;

    const f4* xr4 = (const f4*)(x + (long)node * DIN);
    const f4* wr4 = (const f4*)(&WT[cls][0]);   // 16B-aligned (528B stride)
    float acc = b[cls];
#pragma unroll 8
    for (int k4 = 0; k4 < DIN / 4; ++k4) {
        f4 xv = __builtin_nontemporal_load(xr4 + k4);   // x streamed once
        f4 wv = wr4[k4];
        acc = fmaf(xv.x, wv.x, acc);
        acc = fmaf(xv.y, wv.y, acc);
        acc = fmaf(xv.z, wv.z, acc);
        acc = fmaf(xv.w, wv.w, acc);
    }
    float m = acc;
    for (int off = 8; off; off >>= 1) m = fmaxf(m, __shfl_xor(m, off, 16));
    float s = __expf(acc - m);
    for (int off = 8; off; off >>= 1) s += __shfl_xor(s, off, 16);
    float lb = acc - m - __logf(s);

    logb0[idx] = lb;                                       // f32 (final pass)
    unsigned short su = (unsigned short)(-lb * QS + 0.5f); // seed (lb <= 0)
    seedq[idx] = su;
    bufA[idx]  = su;                                       // iter-0 read buf
    bufB[idx]  = su;                                       // iter-0 write buf
}

// ---------------------------------------------------------------------------
// Edge kernel, swapped-operand MFMA layout (HW-verified rounds 2-8).
// r8's 2-random-transactions-per-edge structure (the measured floor), with
// belief formed ON THE FLY from the seeded agg buffer:
//   - gather: ONE u64 (8B) of Aprev[src] per lane (32B/edge, 2 nodes/line;
//     hot set 3.2MB vs r8's 6.4MB belief array)
//   - v = -A*QINV; mx guard = max over 16 classes (3 max + 2 shuffles)
//   - atomic into PRE-SEEDED Acur (1 contiguous 32B span/edge, r7 form)
//   - RESEED: coalesced copy seedq -> Anext (3.2MB, NT), ready for next iter
// ---------------------------------------------------------------------------
template <bool RD_MSG, bool WR_MSG, bool RESEED>
__global__ __launch_bounds__(256) void k_edges_f(
    const int* __restrict__ esrc, const ull* __restrict__ Aprev,
    ull* __restrict__ Acur, ull* __restrict__ Anext,
    const ull* __restrict__ seedq, const float* __restrict__ Mg,
    ull* __restrict__ msg8)
{
    const int lane = threadIdx.x & 63;
    const int wid  = blockIdx.x * 4 + (threadIdx.x >> 6);
    const int m    = lane & 15;
    const int q    = lane >> 4;

    if (RESEED) {   // re-seed next iteration's write buffer (coalesced)
        int gid = blockIdx.x * 256 + threadIdx.x;
        if (gid < NN * 4)
            __builtin_nontemporal_store(
                __builtin_nontemporal_load(seedq + gid), Anext + gid);
    }

    // atomic permutation constants (lane-invariant)
    const int ed = lane >> 2;                  // edge this lane covers
    const int j4 = lane & 3;                   // u64 index within node row
    const int sl = (j4 << 4) | ed;             // source lane for (ed, j4)

#if USE_1K
    // A-operand fragment: A[row=m][k=4q+j] = M[m][4q+j] (M symmetric)
    v4s mfrag;
#pragma unroll
    for (int jj = 0; jj < 4; ++jj)
        mfrag[jj] = (short)f2bf(Mg[m * CC + 4 * q + jj]);
#endif
    f4 rs = *(const f4*)(Mg + 256 + 4 * q);    // rowsums for k = 4q..4q+3

    // ---- phase 1: independent chain heads (UU chains) ----
    int srcv[UU];
    ull mw[UU];
#pragma unroll
    for (int u = 0; u < UU; ++u) {
        const long blk = (long)wid * UU + u;
        srcv[u] = __builtin_nontemporal_load(esrc + blk * 16 + m);
        if (RD_MSG)
            mw[u] = __builtin_nontemporal_load(msg8 + blk * 64 + q * 16 + (m ^ 1));
    }
    // ---- phase 2: dependent gathers (one 8B u64 per lane) ----
    ull au[UU];
#pragma unroll
    for (int u = 0; u < UU; ++u)
        au[u] = Aprev[(long)srcv[u] * 4 + q];

    // ---- phase 3: compute (UU independent chains in flight) ----
#pragma unroll
    for (int u = 0; u < UU; ++u) {
        const long blk = (long)wid * UU + u;

        // un-normalized belief for classes 4q..4q+3 of src
        float v0 = -(float)(unsigned int)(au[u] & 0xffffu)         * QINV;
        float v1 = -(float)(unsigned int)((au[u] >> 16) & 0xffffu) * QINV;
        float v2 = -(float)(unsigned int)((au[u] >> 32) & 0xffffu) * QINV;
        float v3 = -(float)(unsigned int)(au[u] >> 48)             * QINV;

        float mx = fmaxf(fmaxf(v0, v1), fmaxf(v2, v3));
        mx = fmaxf(mx, __shfl_xor(mx, 16, 64));
        mx = fmaxf(mx, __shfl_xor(mx, 32, 64));

        float mv0 = 0.f, mv1 = 0.f, mv2 = 0.f, mv3 = 0.f;
        if (RD_MSG) {
            mv0 = h2f((unsigned short)(mw[u] & 0xffffu));
            mv1 = h2f((unsigned short)((mw[u] >> 16) & 0xffffu));
            mv2 = h2f((unsigned short)((mw[u] >> 32) & 0xffffu));
            mv3 = h2f((unsigned short)(mw[u] >> 48));
        }

        float e0  = __expf(v0 - mx - mv0);  // t = belief[src] - msg[reverse]
        float e1f = __expf(v1 - mx - mv1);
        float e2  = __expf(v2 - mx - mv2);
        float e3  = __expf(v3 - mx - mv3);

        float Tm = e0 * rs.x;
        Tm = fmaf(e1f, rs.y, Tm);
        Tm = fmaf(e2, rs.z, Tm);
        Tm = fmaf(e3, rs.w, Tm);
        Tm += __shfl_xor(Tm, 16, 64);
        Tm += __shfl_xor(Tm, 32, 64);
        float lT = __logf(Tm);             // log T[edge m], lane-local

        float D0, D1, D2, D3;
#if USE_1K
        v4s a;
        a[0] = (short)f2bf(e0); a[1] = (short)f2bf(e1f);
        a[2] = (short)f2bf(e2); a[3] = (short)f2bf(e3);
        v4f acc = {0.f, 0.f, 0.f, 0.f};
        // swapped operands: D[row=class 4q+i][col=edge m]
        v4f D = __builtin_amdgcn_mfma_f32_16x16x16bf16_1k(mfrag, a, acc, 0, 0, 0);
        D0 = D[0]; D1 = D[1]; D2 = D[2]; D3 = D[3];
#else
        // fallback: cross-quad broadcast + scalar dot (same lane layout)
        float ee[4] = {e0, e1f, e2, e3};
        float g1[4], g2[4], g3[4];
#pragma unroll
        for (int jj = 0; jj < 4; ++jj) {
            g1[jj] = __shfl_xor(ee[jj], 16, 64);
            g2[jj] = __shfl_xor(ee[jj], 32, 64);
            g3[jj] = __shfl_xor(ee[jj], 48, 64);
        }
        float Dv[4];
#pragma unroll
        for (int i = 0; i < 4; ++i) {
            const float* Mr = Mg + (4 * q + i) * CC;
            float d = 0.f;
#pragma unroll
            for (int jj = 0; jj < 4; ++jj) {
                d = fmaf(Mr[4 * q + jj],       ee[jj], d);
                d = fmaf(Mr[4 * (q ^ 1) + jj], g1[jj], d);
                d = fmaf(Mr[4 * (q ^ 2) + jj], g2[jj], d);
                d = fmaf(Mr[4 * (q ^ 3) + jj], g3[jj], d);
            }
            Dv[i] = d;
        }
        D0 = Dv[0]; D1 = Dv[1]; D2 = Dv[2]; D3 = Dv[3];
#endif
        // normalized log-message for edge m, classes 4q..4q+3
        float n0 = __logf(D0) - lT;
        float n1 = __logf(D1) - lT;
        float n2 = __logf(D2) - lT;
        float n3 = __logf(D3) - lT;

        if (WR_MSG) {
            ull w = (ull)pack_h(n0, n1) | ((ull)pack_h(n2, n3) << 32);
            __builtin_nontemporal_store(w, msg8 + blk * 64 + q * 16 + m);
        }

        // dst(edge m) = src(edge m^1): pairs are reciprocal and adjacent
        int dstv = __shfl_xor(srcv[u], 1, 16);

        // u16 fixed-point pack: this lane holds u64 #q of edge m directly
        unsigned int q0 = (unsigned int)(fminf(fmaxf(-n0, 0.f), QCLAMP) * QS + 0.5f);
        unsigned int q1 = (unsigned int)(fminf(fmaxf(-n1, 0.f), QCLAMP) * QS + 0.5f);
        unsigned int q2 = (unsigned int)(fminf(fmaxf(-n2, 0.f), QCLAMP) * QS + 0.5f);
        unsigned int q3 = (unsigned int)(fminf(fmaxf(-n3, 0.f), QCLAMP) * QS + 0.5f);
        ull p = (ull)q0 | ((ull)q1 << 16) | ((ull)q2 << 32) | ((ull)q3 << 48);

        // permute so ONE atomic instruction covers 16 edges x 32B spans
        ull v = __shfl(p, sl, 64);
        int d = __shfl(dstv, ed, 16);        // dst of edge ed (q-invariant)
        atomicAdd(&Acur[(long)d * 4 + j4], v);
    }
}

// ---------------------------------------------------------------------------
// FINAL: out = log_normalize(logb0 - (A - seed)*QINV).  Vectorized x8:
// thread t owns half a node row; row-pair exchange = shfl_xor(1).
// Exact msg sum recovered in integer domain; logb0 read at full f32.
// ---------------------------------------------------------------------------
__global__ __launch_bounds__(256) void k_final(
    const float* __restrict__ logb0, const ull* __restrict__ Acur,
    const ull* __restrict__ seedq, float* __restrict__ out)
{
    const int t = blockIdx.x * 256 + threadIdx.x;
    if (t >= 2 * NN) return;
    const int node = t >> 1;
    const int h    = t & 1;

    const long ab = (long)node * 4 + h * 2;
    ull a0 = Acur[ab],  a1 = Acur[ab + 1];
    ull s0 = seedq[ab], s1 = seedq[ab + 1];

    const long db = (long)node * CC + h * 8;
    f4 l0 = *(const f4*)(logb0 + db);
    f4 l1 = *(const f4*)(logb0 + db + 4);

    float v[8];
#pragma unroll
    for (int i = 0; i < 4; ++i) {
        int d0 = (int)((a0 >> (16 * i)) & 0xffffu) - (int)((s0 >> (16 * i)) & 0xffffu);
        int d1 = (int)((a1 >> (16 * i)) & 0xffffu) - (int)((s1 >> (16 * i)) & 0xffffu);
        v[i]     = fmaf(-(float)d0, QINV, l0[i]);
        v[4 + i] = fmaf(-(float)d1, QINV, l1[i]);
    }
    float mx = v[0];
#pragma unroll
    for (int i = 1; i < 8; ++i) mx = fmaxf(mx, v[i]);
    mx = fmaxf(mx, __shfl_xor(mx, 1, 64));     // other half of the node row

    float s = 0.f;
#pragma unroll
    for (int i = 0; i < 8; ++i) s += __expf(v[i] - mx);
    s += __shfl_xor(s, 1, 64);
    float lz = mx + __logf(s);

    f4 o0, o1;
#pragma unroll
    for (int i = 0; i < 4; ++i) { o0[i] = v[i] - lz; o1[i] = v[4 + i] - lz; }
    *(f4*)(out + db)     = o0;
    *(f4*)(out + db + 4) = o1;
}

// ---------------------------------------------------------------------------
extern "C" void kernel_launch(void* const* d_in, const int* in_sizes, int n_in,
                              void* d_out, int out_size, void* d_ws, size_t ws_size,
                              hipStream_t stream)
{
    const float* x     = (const float*)d_in[0];
    const float* W     = (const float*)d_in[1];
    const float* b     = (const float*)d_in[2];
    const float* param = (const float*)d_in[3];
    const int*   eidx  = (const int*)d_in[4];
    const int*   esrc  = eidx;                 // edst derived via pair shuffle

    // byte-offset layout (all 64B-aligned; u16 buffers = NN*32B each)
    char* ws = (char*)d_ws;
    float* M      = (float*)ws;                        // [0, 1152)
    float* logb0  = (float*)(ws + 4096);               // N*C f32   (6.4 MB)
    ull*   seedq  = (ull*)(ws + 6404096);              // N*C u16   (3.2 MB)
    ull*   bufA   = (ull*)(ws + 9604096);              // N*C u16
    ull*   bufB   = (ull*)(ws + 12804096);             // N*C u16
    ull*   bufC   = (ull*)(ws + 16004096);             // N*C u16
    ull*   msg8   = (ull*)(ws + 19204096);             // NBLKS*64 u64 (51.2 MB)
    float* outp   = (float*)d_out;

    ull* bufs[3] = { bufA, bufB, bufC };

    k_setup<<<NN * CC / 256, 256, 0, stream>>>(
        x, W, b, param, M, logb0, (unsigned short*)seedq,
        (unsigned short*)bufA, (unsigned short*)bufB);

    // rotation: iter k reads bufs[k%3], atomics into bufs[(k+1)%3] (seeded),
    // reseeds bufs[(k+2)%3] for iteration k+1.
    k_edges_f<false, true, true><<<GRID_E, 256, 0, stream>>>(
        esrc, bufs[0], bufs[1], bufs[2], seedq, M, msg8);
    k_edges_f<true, true, true><<<GRID_E, 256, 0, stream>>>(
        esrc, bufs[1], bufs[2], bufs[0], seedq, M, msg8);
    k_edges_f<true, true, true><<<GRID_E, 256, 0, stream>>>(
        esrc, bufs[2], bufs[0], bufs[1], seedq, M, msg8);
    k_edges_f<true, true, true><<<GRID_E, 256, 0, stream>>>(
        esrc, bufs[0], bufs[1], bufs[2], seedq, M, msg8);
    k_edges_f<true, false, false><<<GRID_E, 256, 0, stream>>>(
        esrc, bufs[1], bufs[2], bufs[0], seedq, M, msg8);

    k_final<<<GRID_U, 256, 0, stream>>>(logb0, bufs[2], seedq, outp);
}